// Round 7
// baseline (1285.227 us; speedup 1.0000x reference)
//
#include <hip/hip_runtime.h>
#include <hip/hip_bf16.h>

typedef unsigned short u16;
typedef __attribute__((ext_vector_type(8))) short bf16x8;
typedef __attribute__((ext_vector_type(4))) float f32x4;

#define NE 500000
#define NBLOCKS ((NE + 63) / 64)

// ---------------- d_ws layout ----------------
#define WE0_U 0u        // [128][256]
#define WE1_U 32768u    // [128][128]
#define WE2_U 49152u    // [128][128]
#define WE3_U 65536u    // [16][128]  (rows 10..15 zero)
#define WD0_U 67584u    // [128][32]  (k 5..31 zero)
#define WD1_U 71680u    // [128][128]
#define WD2_U 88064u    // [128][128]
#define WD3_U 104448u   // [256][128]
#define BIAS_F 68608u   // float index base (byte 274432/4)
#define BE0_F 0
#define BE1_F 128
#define BE2_F 256
#define BE3_F 384
#define BD0_F 400
#define BD1_F 528
#define BD2_F 656
#define BD3_F 784
#define NBIAS 1040
#define ACC_BYTE 278592u  // double[2]: rl_sum, kl_sum

__device__ __forceinline__ u16 f2bf(float f) {
  __hip_bfloat16 h = __float2bfloat16(f);
  u16 u;
  __builtin_memcpy(&u, &h, 2);
  return u;
}

// ---------------- prep: transpose weights to bf16 [N][K], copy biases, zero accum ----------------
__global__ void prep_kernel(const float* __restrict__ eW0, const float* __restrict__ eb0,
                            const float* __restrict__ eW1, const float* __restrict__ eb1,
                            const float* __restrict__ eW2, const float* __restrict__ eb2,
                            const float* __restrict__ eW3, const float* __restrict__ eb3,
                            const float* __restrict__ dW0, const float* __restrict__ db0,
                            const float* __restrict__ dW1, const float* __restrict__ db1,
                            const float* __restrict__ dW2, const float* __restrict__ db2,
                            const float* __restrict__ dW3, const float* __restrict__ db3,
                            u16* __restrict__ wsu) {
  int t = blockIdx.x * 256 + threadIdx.x;
  float* wsf = (float*)wsu;
  if (t < 32768) {
    int n = t >> 8, k = t & 255;
    wsu[WE0_U + n * 256 + k] = f2bf(eW0[k * 128 + n]);
  } else if (t < 49152) {
    int i = t - 32768, n = i >> 7, k = i & 127;
    wsu[WE1_U + n * 128 + k] = f2bf(eW1[k * 128 + n]);
  } else if (t < 65536) {
    int i = t - 49152, n = i >> 7, k = i & 127;
    wsu[WE2_U + n * 128 + k] = f2bf(eW2[k * 128 + n]);
  } else if (t < 67584) {
    int i = t - 65536, n = i >> 7, k = i & 127;
    wsu[WE3_U + n * 128 + k] = f2bf(n < 10 ? eW3[k * 10 + n] : 0.f);
  } else if (t < 71680) {
    int i = t - 67584, n = i >> 5, k = i & 31;
    wsu[WD0_U + n * 32 + k] = f2bf(k < 5 ? dW0[k * 128 + n] : 0.f);
  } else if (t < 88064) {
    int i = t - 71680, n = i >> 7, k = i & 127;
    wsu[WD1_U + n * 128 + k] = f2bf(dW1[k * 128 + n]);
  } else if (t < 104448) {
    int i = t - 88064, n = i >> 7, k = i & 127;
    wsu[WD2_U + n * 128 + k] = f2bf(dW2[k * 128 + n]);
  } else if (t < 137216) {
    int i = t - 104448, n = i >> 7, k = i & 127;
    wsu[WD3_U + n * 128 + k] = f2bf(dW3[k * 256 + n]);
  } else if (t < 137216 + NBIAS) {
    int i = t - 137216;
    float v;
    if (i < 128) v = eb0[i];
    else if (i < 256) v = eb1[i - 128];
    else if (i < 384) v = eb2[i - 256];
    else if (i < 400) v = (i - 384 < 10) ? eb3[i - 384] : 0.f;
    else if (i < 528) v = db0[i - 400];
    else if (i < 656) v = db1[i - 528];
    else if (i < 784) v = db2[i - 656];
    else v = db3[i - 784];
    wsf[BIAS_F + i] = v;
  } else if (t < 137216 + NBIAS + 2) {
    ((double*)((char*)wsu + ACC_BYTE))[t - 137216 - NBIAS] = 0.0;
  }
}

// ---------------- helpers ----------------
// LDS activation tiles: [64 rows][128 bf16], XOR-swizzled byte ^= (row&7)<<4
__device__ __forceinline__ bf16x8 ldA(const u16* buf, int row, int k) {
  int byte = (row * 256 + k * 2) ^ ((row & 7) << 4);
  return *(const bf16x8*)((const char*)buf + byte);
}

__device__ __forceinline__ void init_acc(f32x4 acc[8], const float* __restrict__ bias, int j) {
  #pragma unroll
  for (int n = 0; n < 8; ++n) {
    float b = bias[n * 16 + j];
    f32x4 v = {b, b, b, b};
    acc[n] = v;
  }
}

// wave computes 16 rows (rw..rw+15) x 128 cols over K=128
template<int LDW>
__device__ __forceinline__ void gemm_acc(const u16* __restrict__ inb, const u16* __restrict__ Wt,
                                         int k0, f32x4 acc[8], int rw, int g, int j) {
  #pragma unroll
  for (int kk = 0; kk < 4; ++kk) {
    int k = kk * 32 + g * 8;
    bf16x8 a0 = ldA(inb, rw + j, k);
    #pragma unroll
    for (int n = 0; n < 8; ++n) {
      bf16x8 b = *(const bf16x8*)(Wt + (n * 16 + j) * LDW + k0 + k);
      acc[n] = __builtin_amdgcn_mfma_f32_16x16x32_bf16(a0, b, acc[n], 0, 0, 0);
    }
  }
}

// C layout: col = lane&15, row = (lane>>4)*4 + reg
__device__ __forceinline__ void store_act(const f32x4 acc[8], u16* outb, int rw, int g, int j,
                                          bool relu) {
  #pragma unroll
  for (int n = 0; n < 8; ++n)
    #pragma unroll
    for (int r = 0; r < 4; ++r) {
      float v = acc[n][r];
      if (relu) v = fmaxf(v, 0.f);
      int row = rw + g * 4 + r;
      int c = n * 16 + j;
      int byte = (row * 256 + c * 2) ^ ((row & 7) << 4);
      *(u16*)((char*)outb + byte) = f2bf(v);
    }
}

// gather this wave's 16 node rows (fp32) -> bf16 swizzled LDS tile; 4 lanes/row
__device__ __forceinline__ void stage(const float* __restrict__ x, const int* __restrict__ idx,
                                      int e0, u16* buf, int rw, int lane) {
  int rl = rw + (lane >> 2);   // wave-private rows rw..rw+15
  int sub = lane & 3;          // 32-float segment
  int e = e0 + rl;
  if (e >= NE) e = NE - 1;
  int node = idx[e];
  const f32x4* src = (const f32x4*)(x + (size_t)node * 128 + sub * 32);
  #pragma unroll
  for (int c = 0; c < 4; ++c) {
    f32x4 v0 = src[c * 2];
    f32x4 v1 = src[c * 2 + 1];
    bf16x8 o;
    o[0] = (short)f2bf(v0[0]); o[1] = (short)f2bf(v0[1]);
    o[2] = (short)f2bf(v0[2]); o[3] = (short)f2bf(v0[3]);
    o[4] = (short)f2bf(v1[0]); o[5] = (short)f2bf(v1[1]);
    o[6] = (short)f2bf(v1[2]); o[7] = (short)f2bf(v1[3]);
    int col = sub * 32 + c * 8;
    int byte = (rl * 256 + col * 2) ^ ((rl & 7) << 4);
    *(bf16x8*)((char*)buf + byte) = o;
  }
}

// ---------------- main fused kernel: 1 block = 64 edges, 4 waves x 16 rows ----------------
// All LDS tiles are wave-private (wave w touches only rows 16w..16w+15), so NO
// __syncthreads between phases — within-wave ds ordering via compiler lgkmcnt.
// amdgpu_waves_per_eu(4,4): pin allocator target to 4 waves/EU (128 VGPR cap),
// preventing spill-for-occupancy (LDS caps residency at 4 blocks/CU anyway).
__global__ __launch_bounds__(256) __attribute__((amdgpu_waves_per_eu(4, 4)))
void vae_kernel(
    const float* __restrict__ x, const int* __restrict__ rowi, const int* __restrict__ coli,
    const float* __restrict__ eps, const u16* __restrict__ wsu, double* __restrict__ accg,
    float* __restrict__ out) {
  __shared__ __align__(16) u16 bufA[64 * 128];
  __shared__ __align__(16) u16 bufB[64 * 128];
  __shared__ __align__(16) u16 zbuf[64 * 32];   // [row][32], k 5..31 zero
  __shared__ float redr[4], redk[4];

  const float* wsf = (const float*)wsu;
  const int tid = threadIdx.x;
  const int lane = tid & 63;
  const int wave = tid >> 6;
  const int g = lane >> 4;
  const int j = lane & 15;
  const int rw = wave * 16;
  const int e0 = blockIdx.x * 64;

  // zero this wave's zbuf rows (1 b128 store/lane)
  {
    bf16x8 zz = {};
    int zr = rw + (lane >> 2);
    int zc = (lane & 3) * 8;
    *(bf16x8*)(zbuf + zr * 32 + zc) = zz;
  }

  float kl_part = 0.f, rl_part = 0.f;
  f32x4 acc[8];

  // ---- stage both pair halves (wave-private rows; no barrier) ----
  stage(x, rowi, e0, bufA, rw, lane);
  stage(x, coli, e0, bufB, rw, lane);

  // ---- enc0: [64x256] @ eW0 (K halves in A and B) ----
  init_acc(acc, wsf + BIAS_F + BE0_F, j);
  gemm_acc<256>(bufA, wsu + WE0_U, 0, acc, rw, g, j);
  gemm_acc<256>(bufB, wsu + WE0_U, 128, acc, rw, g, j);
  store_act(acc, bufA, rw, g, j, true);

  // ---- enc1: A -> B ----
  init_acc(acc, wsf + BIAS_F + BE1_F, j);
  gemm_acc<128>(bufA, wsu + WE1_U, 0, acc, rw, g, j);
  store_act(acc, bufB, rw, g, j, true);

  // ---- enc2: B -> A ----
  init_acc(acc, wsf + BIAS_F + BE2_F, j);
  gemm_acc<128>(bufB, wsu + WE2_U, 0, acc, rw, g, j);
  store_act(acc, bufA, rw, g, j, true);

  // ---- enc3: A -> mu/logvar (N=16: cols 0..4 mu, 5..9 logvar) ----
  f32x4 a3;
  {
    float b3 = wsf[BIAS_F + BE3_F + j];
    f32x4 v = {b3, b3, b3, b3};
    a3 = v;
    #pragma unroll
    for (int kk = 0; kk < 4; ++kk) {
      int k = kk * 32 + g * 8;
      bf16x8 q0 = ldA(bufA, rw + j, k);
      bf16x8 b = *(const bf16x8*)(wsu + WE3_U + j * 128 + k);
      a3 = __builtin_amdgcn_mfma_f32_16x16x32_bf16(q0, b, a3, 0, 0, 0);
    }
  }

  // ---- reparameterization + KL (shuffles stay within the wave) ----
  {
    int src = g * 16 + ((j + 5) & 15);
    #pragma unroll
    for (int r = 0; r < 4; ++r) {
      float muv = a3[r];
      float lvv = __shfl(a3[r], src, 64);
      if (j < 5) {
        int row = rw + g * 4 + r;
        int e = e0 + row;
        int ec = e < NE ? e : NE - 1;
        float stdv = __expf(0.5f * lvv);
        float zv = muv + eps[(size_t)ec * 5 + j] * stdv;
        zbuf[row * 32 + j] = f2bf(zv);
        if (e < NE) kl_part += 1.0f + lvv - muv * muv - __expf(lvv);
      }
    }
  }

  // hoist loss node indices (independent loads, hide latency under decoder)
  int rn[4], cn[4];
  #pragma unroll
  for (int r = 0; r < 4; ++r) {
    int e = e0 + rw + g * 4 + r;
    int ec = e < NE ? e : NE - 1;
    rn[r] = rowi[ec];
    cn[r] = coli[ec];
  }

  // ---- dec0: z[16x5 pad 32] @ dW0 -> B ----
  init_acc(acc, wsf + BIAS_F + BD0_F, j);
  {
    int k = g * 8;
    bf16x8 q0 = *(const bf16x8*)(zbuf + (rw + j) * 32 + k);
    #pragma unroll
    for (int n = 0; n < 8; ++n) {
      bf16x8 b = *(const bf16x8*)(wsu + WD0_U + (n * 16 + j) * 32 + k);
      acc[n] = __builtin_amdgcn_mfma_f32_16x16x32_bf16(q0, b, acc[n], 0, 0, 0);
    }
  }
  store_act(acc, bufB, rw, g, j, true);

  // ---- dec1: B -> A ----
  init_acc(acc, wsf + BIAS_F + BD1_F, j);
  gemm_acc<128>(bufB, wsu + WD1_U, 0, acc, rw, g, j);
  store_act(acc, bufA, rw, g, j, true);

  // ---- dec2: A -> B ----
  init_acc(acc, wsf + BIAS_F + BD2_F, j);
  gemm_acc<128>(bufA, wsu + WD2_U, 0, acc, rw, g, j);
  store_act(acc, bufB, rw, g, j, true);

  // ---- dec3 (N=256 in two halves) fused with recon loss ----
  float rlsq[4] = {0.f, 0.f, 0.f, 0.f};
  #pragma unroll
  for (int nh = 0; nh < 2; ++nh) {
    init_acc(acc, wsf + BIAS_F + BD3_F + nh * 128, j);
    #pragma unroll
    for (int kk = 0; kk < 4; ++kk) {
      int k = kk * 32 + g * 8;
      bf16x8 q0 = ldA(bufB, rw + j, k);
      #pragma unroll
      for (int n = 0; n < 8; ++n) {
        bf16x8 b = *(const bf16x8*)(wsu + WD3_U + (nh * 128 + n * 16 + j) * 128 + k);
        acc[n] = __builtin_amdgcn_mfma_f32_16x16x32_bf16(q0, b, acc[n], 0, 0, 0);
      }
    }
    #pragma unroll
    for (int n = 0; n < 8; ++n)
      #pragma unroll
      for (int r = 0; r < 4; ++r) {
        int c = nh * 128 + n * 16 + j;
        int node = (nh == 0) ? rn[r] : cn[r];
        float pv = x[(size_t)node * 128 + (c & 127)];
        float d = acc[n][r] - pv;
        rlsq[r] += d * d;
      }
  }

  // per-row reduce over 16 col-lanes -> rl, affinity
  #pragma unroll
  for (int r = 0; r < 4; ++r) {
    float v = rlsq[r];
    v += __shfl_xor(v, 1);
    v += __shfl_xor(v, 2);
    v += __shfl_xor(v, 4);
    v += __shfl_xor(v, 8);
    if (j == 0) {
      int e = e0 + rw + g * 4 + r;
      if (e < NE) {
        float rl = sqrtf(v);
        out[e] = 1.0f / (1.0f + 3.5f * rl);
        rl_part += rl;
      }
    }
  }

  // ---- block reduction (the ONLY barrier) + global double atomics ----
  float kv = kl_part, rv = rl_part;
  #pragma unroll
  for (int msk = 1; msk < 64; msk <<= 1) {
    kv += __shfl_xor(kv, msk);
    rv += __shfl_xor(rv, msk);
  }
  if (lane == 0) {
    redk[wave] = kv;
    redr[wave] = rv;
  }
  __syncthreads();
  if (tid == 0) {
    atomicAdd(&accg[0], (double)(redr[0] + redr[1] + redr[2] + redr[3]));
    atomicAdd(&accg[1], (double)(redk[0] + redk[1] + redk[2] + redk[3]));
  }
}

// ---------------- finalize ----------------
__global__ void fin_kernel(const double* __restrict__ accg, float* __restrict__ out) {
  if (threadIdx.x == 0) {
    out[NE] = (float)(accg[0] / (double)NE);
    out[NE + 1] = (float)(accg[1] * (-0.5 * 10.0 / ((double)NE * 5.0)));
  }
}

extern "C" void kernel_launch(void* const* d_in, const int* in_sizes, int n_in,
                              void* d_out, int out_size, void* d_ws, size_t ws_size,
                              hipStream_t stream) {
  (void)in_sizes; (void)n_in; (void)out_size; (void)ws_size;
  const float* x   = (const float*)d_in[0];
  const int*   row = (const int*)d_in[1];
  const int*   col = (const int*)d_in[2];
  const float* eps = (const float*)d_in[3];
  u16* wsu = (u16*)d_ws;
  double* accg = (double*)((char*)d_ws + ACC_BYTE);
  float* out = (float*)d_out;

  prep_kernel<<<541, 256, 0, stream>>>(
      (const float*)d_in[4],  (const float*)d_in[5],  (const float*)d_in[6],  (const float*)d_in[7],
      (const float*)d_in[8],  (const float*)d_in[9],  (const float*)d_in[10], (const float*)d_in[11],
      (const float*)d_in[12], (const float*)d_in[13], (const float*)d_in[14], (const float*)d_in[15],
      (const float*)d_in[16], (const float*)d_in[17], (const float*)d_in[18], (const float*)d_in[19],
      wsu);
  vae_kernel<<<NBLOCKS, 256, 0, stream>>>(x, row, col, eps, wsu, accg, out);
  fin_kernel<<<1, 64, 0, stream>>>(accg, out);
}

// Round 8
// 801.551 us; speedup vs baseline: 1.6034x; 1.6034x over previous
//
#include <hip/hip_runtime.h>
#include <hip/hip_bf16.h>

typedef unsigned short u16;
typedef __attribute__((ext_vector_type(8))) short bf16x8;
typedef __attribute__((ext_vector_type(4))) float f32x4;

#define NE 500000
#define NBLOCKS ((NE + 127) / 128)

// ---------------- d_ws layout ----------------
#define WE0_U 0u        // [128][256]
#define WE1_U 32768u    // [128][128]
#define WE2_U 49152u    // [128][128]
#define WE3_U 65536u    // [16][128]  (rows 10..15 zero)
#define WD0_U 67584u    // [128][32]  (k 5..31 zero)
#define WD1_U 71680u    // [128][128]
#define WD2_U 88064u    // [128][128]
#define WD3_U 104448u   // [256][128]
#define BIAS_F 68608u   // float index base (byte 274432/4)
#define BE0_F 0
#define BE1_F 128
#define BE2_F 256
#define BE3_F 384
#define BD0_F 400
#define BD1_F 528
#define BD2_F 656
#define BD3_F 784
#define NBIAS 1040
#define ACC_BYTE 278592u  // double[2]: rl_sum, kl_sum

__device__ __forceinline__ u16 f2bf(float f) {
  __hip_bfloat16 h = __float2bfloat16(f);
  u16 u;
  __builtin_memcpy(&u, &h, 2);
  return u;
}

__device__ __forceinline__ f32x4 bcast4(float b) {
  f32x4 v = {b, b, b, b};
  return v;
}

// ---------------- prep: transpose weights to bf16 [N][K], copy biases, zero accum ----------------
__global__ void prep_kernel(const float* __restrict__ eW0, const float* __restrict__ eb0,
                            const float* __restrict__ eW1, const float* __restrict__ eb1,
                            const float* __restrict__ eW2, const float* __restrict__ eb2,
                            const float* __restrict__ eW3, const float* __restrict__ eb3,
                            const float* __restrict__ dW0, const float* __restrict__ db0,
                            const float* __restrict__ dW1, const float* __restrict__ db1,
                            const float* __restrict__ dW2, const float* __restrict__ db2,
                            const float* __restrict__ dW3, const float* __restrict__ db3,
                            u16* __restrict__ wsu) {
  int t = blockIdx.x * 256 + threadIdx.x;
  float* wsf = (float*)wsu;
  if (t < 32768) {
    int n = t >> 8, k = t & 255;
    wsu[WE0_U + n * 256 + k] = f2bf(eW0[k * 128 + n]);
  } else if (t < 49152) {
    int i = t - 32768, n = i >> 7, k = i & 127;
    wsu[WE1_U + n * 128 + k] = f2bf(eW1[k * 128 + n]);
  } else if (t < 65536) {
    int i = t - 49152, n = i >> 7, k = i & 127;
    wsu[WE2_U + n * 128 + k] = f2bf(eW2[k * 128 + n]);
  } else if (t < 67584) {
    int i = t - 65536, n = i >> 7, k = i & 127;
    wsu[WE3_U + n * 128 + k] = f2bf(n < 10 ? eW3[k * 10 + n] : 0.f);
  } else if (t < 71680) {
    int i = t - 67584, n = i >> 5, k = i & 31;
    wsu[WD0_U + n * 32 + k] = f2bf(k < 5 ? dW0[k * 128 + n] : 0.f);
  } else if (t < 88064) {
    int i = t - 71680, n = i >> 7, k = i & 127;
    wsu[WD1_U + n * 128 + k] = f2bf(dW1[k * 128 + n]);
  } else if (t < 104448) {
    int i = t - 88064, n = i >> 7, k = i & 127;
    wsu[WD2_U + n * 128 + k] = f2bf(dW2[k * 128 + n]);
  } else if (t < 137216) {
    int i = t - 104448, n = i >> 7, k = i & 127;
    wsu[WD3_U + n * 128 + k] = f2bf(dW3[k * 256 + n]);
  } else if (t < 137216 + NBIAS) {
    int i = t - 137216;
    float v;
    if (i < 128) v = eb0[i];
    else if (i < 256) v = eb1[i - 128];
    else if (i < 384) v = eb2[i - 256];
    else if (i < 400) v = (i - 384 < 10) ? eb3[i - 384] : 0.f;
    else if (i < 528) v = db0[i - 400];
    else if (i < 656) v = db1[i - 528];
    else if (i < 784) v = db2[i - 656];
    else v = db3[i - 784];
    wsf[BIAS_F + i] = v;
  } else if (t < 137216 + NBIAS + 2) {
    ((double*)((char*)wsu + ACC_BYTE))[t - 137216 - NBIAS] = 0.0;
  }
}

// ---------------- helpers ----------------
// LDS activation tiles: [128 rows][128 bf16], XOR-swizzled byte ^= (row&7)<<4
__device__ __forceinline__ bf16x8 ldA(const u16* buf, int row, int k) {
  int byte = (row * 256 + k * 2) ^ ((row & 7) << 4);
  return *(const bf16x8*)((const char*)buf + byte);
}

// half-N accumulators: 32 rows (rw..rw+31) x 64 cols (half nh), peak live 32 VGPR
__device__ __forceinline__ void init_half(f32x4 acc[2][4], const float* __restrict__ bias,
                                          int nh, int j) {
  #pragma unroll
  for (int n = 0; n < 4; ++n) {
    f32x4 v = bcast4(bias[nh * 64 + n * 16 + j]);
    acc[0][n] = v;
    acc[1][n] = v;
  }
}

template<int LDW>
__device__ __forceinline__ void gemm_half(const u16* __restrict__ inb, const u16* __restrict__ Wt,
                                          int k0, int nh, f32x4 acc[2][4], int rw, int g, int j) {
  #pragma unroll
  for (int kk = 0; kk < 4; ++kk) {
    int k = kk * 32 + g * 8;
    bf16x8 a0 = ldA(inb, rw + j, k);
    bf16x8 a1 = ldA(inb, rw + 16 + j, k);
    #pragma unroll
    for (int n = 0; n < 4; ++n) {
      bf16x8 b = *(const bf16x8*)(Wt + ((nh * 4 + n) * 16 + j) * LDW + k0 + k);
      acc[0][n] = __builtin_amdgcn_mfma_f32_16x16x32_bf16(a0, b, acc[0][n], 0, 0, 0);
      acc[1][n] = __builtin_amdgcn_mfma_f32_16x16x32_bf16(a1, b, acc[1][n], 0, 0, 0);
    }
  }
}

// C layout: col = lane&15, row = (lane>>4)*4 + reg
__device__ __forceinline__ void store_half(const f32x4 acc[2][4], u16* outb, int rw, int nh,
                                           int g, int j, bool relu) {
  #pragma unroll
  for (int m = 0; m < 2; ++m)
    #pragma unroll
    for (int n = 0; n < 4; ++n)
      #pragma unroll
      for (int r = 0; r < 4; ++r) {
        float v = acc[m][n][r];
        if (relu) v = fmaxf(v, 0.f);
        int row = rw + m * 16 + g * 4 + r;
        int c = nh * 64 + n * 16 + j;
        int byte = (row * 256 + c * 2) ^ ((row & 7) << 4);
        *(u16*)((char*)outb + byte) = f2bf(v);
      }
}

// K=128 N=128 layer, in -> out (must be distinct buffers), n-split for low regs
__device__ __forceinline__ void layer128(const u16* __restrict__ inb, u16* __restrict__ outb,
                                         const u16* __restrict__ Wt, const float* __restrict__ bias,
                                         int rw, int g, int j) {
  #pragma unroll
  for (int nh = 0; nh < 2; ++nh) {
    f32x4 acc[2][4];
    init_half(acc, bias, nh, j);
    gemm_half<128>(inb, Wt, 0, nh, acc, rw, g, j);
    store_half(acc, outb, rw, nh, g, j, true);
  }
}

// gather this wave's 32 node rows (fp32) -> bf16 swizzled LDS tile; 2 lanes/row
__device__ __forceinline__ void stage(const float* __restrict__ x, const int* __restrict__ idx,
                                      int e0, u16* buf, int rw, int lane) {
  int rl = rw + (lane >> 1);   // wave-private rows rw..rw+31
  int sub = lane & 1;          // 64-float half of the feature row
  int e = e0 + rl;
  if (e >= NE) e = NE - 1;
  int node = idx[e];
  const f32x4* src = (const f32x4*)(x + (size_t)node * 128 + sub * 64);
  #pragma unroll
  for (int c = 0; c < 8; ++c) {
    f32x4 v0 = src[c * 2];
    f32x4 v1 = src[c * 2 + 1];
    bf16x8 o;
    o[0] = (short)f2bf(v0[0]); o[1] = (short)f2bf(v0[1]);
    o[2] = (short)f2bf(v0[2]); o[3] = (short)f2bf(v0[3]);
    o[4] = (short)f2bf(v1[0]); o[5] = (short)f2bf(v1[1]);
    o[6] = (short)f2bf(v1[2]); o[7] = (short)f2bf(v1[3]);
    int col = sub * 64 + c * 8;
    int byte = (rl * 256 + col * 2) ^ ((rl & 7) << 4);
    *(bf16x8*)((char*)buf + byte) = o;
  }
}

// ---------------- main fused kernel: 1 block = 128 edges, 4 waves x 32 wave-private rows ----
// No inter-phase barriers (all LDS rows wave-private; per-wave DS ops are in-order —
// verified correct in rounds 4/7). launch_bounds(256,2) empirically yields 128 VGPRs
// (round 1); n-split keeps peak live ~110 < 128 => no scratch spill.
__global__ __launch_bounds__(256, 2) void vae_kernel(
    const float* __restrict__ x, const int* __restrict__ rowi, const int* __restrict__ coli,
    const float* __restrict__ eps, const u16* __restrict__ wsu, double* __restrict__ accg,
    float* __restrict__ out) {
  __shared__ __align__(16) u16 bufA[128 * 128];  // 32 KB
  __shared__ __align__(16) u16 bufB[128 * 128];  // 32 KB
  __shared__ __align__(16) u16 zbuf[128 * 32];   // 8 KB, [row][32], k 5..31 zero
  __shared__ float redr[4], redk[4];

  const float* wsf = (const float*)wsu;
  const int tid = threadIdx.x;
  const int lane = tid & 63;
  const int wave = tid >> 6;
  const int g = lane >> 4;
  const int j = lane & 15;
  const int rw = wave * 32;
  const int e0 = blockIdx.x * 128;

  // zero this wave's zbuf rows (2 lanes/row, 2 b128 stores/lane)
  {
    bf16x8 zz = {};
    int zr = rw + (lane >> 1);
    int zc = (lane & 1) * 16;
    *(bf16x8*)(zbuf + zr * 32 + zc) = zz;
    *(bf16x8*)(zbuf + zr * 32 + zc + 8) = zz;
  }

  float kl_part = 0.f, rl_part = 0.f;

  // ---- stage both pair halves (wave-private rows; no barrier) ----
  stage(x, rowi, e0, bufA, rw, lane);
  stage(x, coli, e0, bufB, rw, lane);

  // ---- enc0: [128x256] @ eW0 (K halves in A and B), full N=128, write back to A ----
  {
    f32x4 acc8[2][8];
    #pragma unroll
    for (int n = 0; n < 8; ++n) {
      f32x4 v = bcast4(wsf[BIAS_F + BE0_F + n * 16 + j]);
      acc8[0][n] = v;
      acc8[1][n] = v;
    }
    #pragma unroll
    for (int kk = 0; kk < 4; ++kk) {
      int k = kk * 32 + g * 8;
      bf16x8 a0 = ldA(bufA, rw + j, k);
      bf16x8 a1 = ldA(bufA, rw + 16 + j, k);
      #pragma unroll
      for (int n = 0; n < 8; ++n) {
        bf16x8 b = *(const bf16x8*)(wsu + WE0_U + (n * 16 + j) * 256 + k);
        acc8[0][n] = __builtin_amdgcn_mfma_f32_16x16x32_bf16(a0, b, acc8[0][n], 0, 0, 0);
        acc8[1][n] = __builtin_amdgcn_mfma_f32_16x16x32_bf16(a1, b, acc8[1][n], 0, 0, 0);
      }
    }
    #pragma unroll
    for (int kk = 0; kk < 4; ++kk) {
      int k = kk * 32 + g * 8;
      bf16x8 a0 = ldA(bufB, rw + j, k);
      bf16x8 a1 = ldA(bufB, rw + 16 + j, k);
      #pragma unroll
      for (int n = 0; n < 8; ++n) {
        bf16x8 b = *(const bf16x8*)(wsu + WE0_U + (n * 16 + j) * 256 + 128 + k);
        acc8[0][n] = __builtin_amdgcn_mfma_f32_16x16x32_bf16(a0, b, acc8[0][n], 0, 0, 0);
        acc8[1][n] = __builtin_amdgcn_mfma_f32_16x16x32_bf16(a1, b, acc8[1][n], 0, 0, 0);
      }
    }
    // write full width back into bufA (all reads of A by this wave already issued; per-wave DS in-order)
    #pragma unroll
    for (int m = 0; m < 2; ++m)
      #pragma unroll
      for (int n = 0; n < 8; ++n)
        #pragma unroll
        for (int r = 0; r < 4; ++r) {
          float v = fmaxf(acc8[m][n][r], 0.f);
          int row = rw + m * 16 + g * 4 + r;
          int c = n * 16 + j;
          int byte = (row * 256 + c * 2) ^ ((row & 7) << 4);
          *(u16*)((char*)bufA + byte) = f2bf(v);
        }
  }

  // ---- enc1: A -> B ;  enc2: B -> A ----
  layer128(bufA, bufB, wsu + WE1_U, wsf + BIAS_F + BE1_F, rw, g, j);
  layer128(bufB, bufA, wsu + WE2_U, wsf + BIAS_F + BE2_F, rw, g, j);

  // ---- enc3: A -> mu/logvar (N=16: cols 0..4 mu, 5..9 logvar) ----
  f32x4 a3[2];
  {
    f32x4 v = bcast4(wsf[BIAS_F + BE3_F + j]);
    a3[0] = v;
    a3[1] = v;
    #pragma unroll
    for (int kk = 0; kk < 4; ++kk) {
      int k = kk * 32 + g * 8;
      bf16x8 q0 = ldA(bufA, rw + j, k);
      bf16x8 q1 = ldA(bufA, rw + 16 + j, k);
      bf16x8 b = *(const bf16x8*)(wsu + WE3_U + j * 128 + k);
      a3[0] = __builtin_amdgcn_mfma_f32_16x16x32_bf16(q0, b, a3[0], 0, 0, 0);
      a3[1] = __builtin_amdgcn_mfma_f32_16x16x32_bf16(q1, b, a3[1], 0, 0, 0);
    }
  }

  // ---- reparameterization + KL (shuffles within wave) ----
  {
    int src = g * 16 + ((j + 5) & 15);
    #pragma unroll
    for (int m = 0; m < 2; ++m)
      #pragma unroll
      for (int r = 0; r < 4; ++r) {
        float muv = a3[m][r];
        float lvv = __shfl(a3[m][r], src, 64);
        if (j < 5) {
          int row = rw + m * 16 + g * 4 + r;
          int e = e0 + row;
          int ec = e < NE ? e : NE - 1;
          float stdv = __expf(0.5f * lvv);
          float zv = muv + eps[(size_t)ec * 5 + j] * stdv;
          zbuf[row * 32 + j] = f2bf(zv);
          if (e < NE) kl_part += 1.0f + lvv - muv * muv - __expf(lvv);
        }
      }
  }

  // ---- dec0: z[32x5 pad 32] @ dW0 -> B (n-split) ----
  #pragma unroll
  for (int nh = 0; nh < 2; ++nh) {
    f32x4 acc[2][4];
    init_half(acc, wsf + BIAS_F + BD0_F, nh, j);
    int k = g * 8;
    bf16x8 q0 = *(const bf16x8*)(zbuf + (rw + j) * 32 + k);
    bf16x8 q1 = *(const bf16x8*)(zbuf + (rw + 16 + j) * 32 + k);
    #pragma unroll
    for (int n = 0; n < 4; ++n) {
      bf16x8 b = *(const bf16x8*)(wsu + WD0_U + ((nh * 4 + n) * 16 + j) * 32 + k);
      acc[0][n] = __builtin_amdgcn_mfma_f32_16x16x32_bf16(q0, b, acc[0][n], 0, 0, 0);
      acc[1][n] = __builtin_amdgcn_mfma_f32_16x16x32_bf16(q1, b, acc[1][n], 0, 0, 0);
    }
    store_half(acc, bufB, rw, nh, g, j, true);
  }

  // ---- dec1: B -> A ;  dec2: A -> B ----
  layer128(bufB, bufA, wsu + WD1_U, wsf + BIAS_F + BD1_F, rw, g, j);
  layer128(bufA, bufB, wsu + WD2_U, wsf + BIAS_F + BD2_F, rw, g, j);

  // ---- loss node indices ----
  int rn[2][4], cn[2][4];
  #pragma unroll
  for (int m = 0; m < 2; ++m)
    #pragma unroll
    for (int r = 0; r < 4; ++r) {
      int e = e0 + rw + m * 16 + g * 4 + r;
      int ec = e < NE ? e : NE - 1;
      rn[m][r] = rowi[ec];
      cn[m][r] = coli[ec];
    }

  // ---- dec3 (N=256 in 4 quarters) fused with recon loss ----
  float rlsq[2][4] = {{0.f, 0.f, 0.f, 0.f}, {0.f, 0.f, 0.f, 0.f}};
  #pragma unroll
  for (int qh = 0; qh < 4; ++qh) {
    f32x4 acc[2][4];
    init_half(acc, wsf + BIAS_F + BD3_F, qh, j);
    gemm_half<128>(bufB, wsu + WD3_U, 0, qh, acc, rw, g, j);
    #pragma unroll
    for (int m = 0; m < 2; ++m)
      #pragma unroll
      for (int n = 0; n < 4; ++n)
        #pragma unroll
        for (int r = 0; r < 4; ++r) {
          int c = qh * 64 + n * 16 + j;
          int node = (c < 128) ? rn[m][r] : cn[m][r];
          float pv = x[(size_t)node * 128 + (c & 127)];
          float d = acc[m][n][r] - pv;
          rlsq[m][r] += d * d;
        }
  }

  // per-row reduce over 16 col-lanes -> rl, affinity
  #pragma unroll
  for (int m = 0; m < 2; ++m)
    #pragma unroll
    for (int r = 0; r < 4; ++r) {
      float v = rlsq[m][r];
      v += __shfl_xor(v, 1);
      v += __shfl_xor(v, 2);
      v += __shfl_xor(v, 4);
      v += __shfl_xor(v, 8);
      if (j == 0) {
        int e = e0 + rw + m * 16 + g * 4 + r;
        if (e < NE) {
          float rl = sqrtf(v);
          out[e] = 1.0f / (1.0f + 3.5f * rl);
          rl_part += rl;
        }
      }
    }

  // ---- block reduction (the ONLY barrier) + global double atomics ----
  float kv = kl_part, rv = rl_part;
  #pragma unroll
  for (int msk = 1; msk < 64; msk <<= 1) {
    kv += __shfl_xor(kv, msk);
    rv += __shfl_xor(rv, msk);
  }
  if (lane == 0) {
    redk[wave] = kv;
    redr[wave] = rv;
  }
  __syncthreads();
  if (tid == 0) {
    atomicAdd(&accg[0], (double)(redr[0] + redr[1] + redr[2] + redr[3]));
    atomicAdd(&accg[1], (double)(redk[0] + redk[1] + redk[2] + redk[3]));
  }
}

// ---------------- finalize ----------------
__global__ void fin_kernel(const double* __restrict__ accg, float* __restrict__ out) {
  if (threadIdx.x == 0) {
    out[NE] = (float)(accg[0] / (double)NE);
    out[NE + 1] = (float)(accg[1] * (-0.5 * 10.0 / ((double)NE * 5.0)));
  }
}

extern "C" void kernel_launch(void* const* d_in, const int* in_sizes, int n_in,
                              void* d_out, int out_size, void* d_ws, size_t ws_size,
                              hipStream_t stream) {
  (void)in_sizes; (void)n_in; (void)out_size; (void)ws_size;
  const float* x   = (const float*)d_in[0];
  const int*   row = (const int*)d_in[1];
  const int*   col = (const int*)d_in[2];
  const float* eps = (const float*)d_in[3];
  u16* wsu = (u16*)d_ws;
  double* accg = (double*)((char*)d_ws + ACC_BYTE);
  float* out = (float*)d_out;

  prep_kernel<<<541, 256, 0, stream>>>(
      (const float*)d_in[4],  (const float*)d_in[5],  (const float*)d_in[6],  (const float*)d_in[7],
      (const float*)d_in[8],  (const float*)d_in[9],  (const float*)d_in[10], (const float*)d_in[11],
      (const float*)d_in[12], (const float*)d_in[13], (const float*)d_in[14], (const float*)d_in[15],
      (const float*)d_in[16], (const float*)d_in[17], (const float*)d_in[18], (const float*)d_in[19],
      wsu);
  vae_kernel<<<NBLOCKS, 256, 0, stream>>>(x, row, col, eps, wsu, accg, out);
  fin_kernel<<<1, 64, 0, stream>>>(accg, out);
}

// Round 10
// 769.423 us; speedup vs baseline: 1.6704x; 1.0418x over previous
//
#include <hip/hip_runtime.h>
#include <hip/hip_bf16.h>

typedef unsigned short u16;
typedef __attribute__((ext_vector_type(8))) short bf16x8;
typedef __attribute__((ext_vector_type(4))) float f32x4;

#define NE 500000
#define NBLOCKS ((NE + 127) / 128)

// ---------------- d_ws layout ----------------
#define WE0_U 0u        // [128][256]
#define WE1_U 32768u    // [128][128]
#define WE2_U 49152u    // [128][128]
#define WE3_U 65536u    // [16][128]  (rows 10..15 zero)
#define WD0_U 67584u    // [128][32]  (k 5..31 zero)
#define WD1_U 71680u    // [128][128]
#define WD2_U 88064u    // [128][128]
#define WD3_U 104448u   // [256][128]
#define BIAS_F 68608u   // float index base (byte 274432/4)
#define BE0_F 0
#define BE1_F 128
#define BE2_F 256
#define BE3_F 384
#define BD0_F 400
#define BD1_F 528
#define BD2_F 656
#define BD3_F 784
#define NBIAS 1040
#define ACC_BYTE 278592u  // double[2]: rl_sum, kl_sum

__device__ __forceinline__ u16 f2bf(float f) {
  __hip_bfloat16 h = __float2bfloat16(f);
  u16 u;
  __builtin_memcpy(&u, &h, 2);
  return u;
}

__device__ __forceinline__ f32x4 bcast4(float b) {
  f32x4 v = {b, b, b, b};
  return v;
}

// ---------------- prep: transpose weights to bf16 [N][K], copy biases, zero accum ----------------
__global__ void prep_kernel(const float* __restrict__ eW0, const float* __restrict__ eb0,
                            const float* __restrict__ eW1, const float* __restrict__ eb1,
                            const float* __restrict__ eW2, const float* __restrict__ eb2,
                            const float* __restrict__ eW3, const float* __restrict__ eb3,
                            const float* __restrict__ dW0, const float* __restrict__ db0,
                            const float* __restrict__ dW1, const float* __restrict__ db1,
                            const float* __restrict__ dW2, const float* __restrict__ db2,
                            const float* __restrict__ dW3, const float* __restrict__ db3,
                            u16* __restrict__ wsu) {
  int t = blockIdx.x * 256 + threadIdx.x;
  float* wsf = (float*)wsu;
  if (t < 32768) {
    int n = t >> 8, k = t & 255;
    wsu[WE0_U + n * 256 + k] = f2bf(eW0[k * 128 + n]);
  } else if (t < 49152) {
    int i = t - 32768, n = i >> 7, k = i & 127;
    wsu[WE1_U + n * 128 + k] = f2bf(eW1[k * 128 + n]);
  } else if (t < 65536) {
    int i = t - 49152, n = i >> 7, k = i & 127;
    wsu[WE2_U + n * 128 + k] = f2bf(eW2[k * 128 + n]);
  } else if (t < 67584) {
    int i = t - 65536, n = i >> 7, k = i & 127;
    wsu[WE3_U + n * 128 + k] = f2bf(n < 10 ? eW3[k * 10 + n] : 0.f);
  } else if (t < 71680) {
    int i = t - 67584, n = i >> 5, k = i & 31;
    wsu[WD0_U + n * 32 + k] = f2bf(k < 5 ? dW0[k * 128 + n] : 0.f);
  } else if (t < 88064) {
    int i = t - 71680, n = i >> 7, k = i & 127;
    wsu[WD1_U + n * 128 + k] = f2bf(dW1[k * 128 + n]);
  } else if (t < 104448) {
    int i = t - 88064, n = i >> 7, k = i & 127;
    wsu[WD2_U + n * 128 + k] = f2bf(dW2[k * 128 + n]);
  } else if (t < 137216) {
    int i = t - 104448, n = i >> 7, k = i & 127;
    wsu[WD3_U + n * 128 + k] = f2bf(dW3[k * 256 + n]);
  } else if (t < 137216 + NBIAS) {
    int i = t - 137216;
    float v;
    if (i < 128) v = eb0[i];
    else if (i < 256) v = eb1[i - 128];
    else if (i < 384) v = eb2[i - 256];
    else if (i < 400) v = (i - 384 < 10) ? eb3[i - 384] : 0.f;
    else if (i < 528) v = db0[i - 400];
    else if (i < 656) v = db1[i - 528];
    else if (i < 784) v = db2[i - 656];
    else v = db3[i - 784];
    wsf[BIAS_F + i] = v;
  } else if (t < 137216 + NBIAS + 2) {
    ((double*)((char*)wsu + ACC_BYTE))[t - 137216 - NBIAS] = 0.0;
  }
}

// ---------------- helpers ----------------
// LDS activation tile: [128 rows][128 bf16], XOR-swizzled byte ^= (row&7)<<4
__device__ __forceinline__ bf16x8 ldA(const u16* buf, int row, int k) {
  int byte = (row * 256 + k * 2) ^ ((row & 7) << 4);
  return *(const bf16x8*)((const char*)buf + byte);
}

// load this wave's 8 A-fragments (rows rw+j, rw+16+j for K=0..127) into registers
__device__ __forceinline__ void load_frags(const u16* buf, int rw, int g, int j, bf16x8 f[8]) {
  #pragma unroll
  for (int kk = 0; kk < 4; ++kk) {
    int k = kk * 32 + g * 8;
    f[kk * 2]     = ldA(buf, rw + j, k);
    f[kk * 2 + 1] = ldA(buf, rw + 16 + j, k);
  }
}

// half-N accumulators: 32 rows x 64 cols (quarter nh for dec3), peak live 32 VGPR
__device__ __forceinline__ void init_half(f32x4 acc[2][4], const float* __restrict__ bias,
                                          int nh, int j) {
  #pragma unroll
  for (int n = 0; n < 4; ++n) {
    f32x4 v = bcast4(bias[nh * 64 + n * 16 + j]);
    acc[0][n] = v;
    acc[1][n] = v;
  }
}

// K=128 GEMM from register A-fragments (Wt leading dim 128)
__device__ __forceinline__ void gemm_half_f(const bf16x8 f[8], const u16* __restrict__ Wt,
                                            int nh, f32x4 acc[2][4], int g, int j) {
  #pragma unroll
  for (int kk = 0; kk < 4; ++kk) {
    int k = kk * 32 + g * 8;
    #pragma unroll
    for (int n = 0; n < 4; ++n) {
      bf16x8 b = *(const bf16x8*)(Wt + ((nh * 4 + n) * 16 + j) * 128 + k);
      acc[0][n] = __builtin_amdgcn_mfma_f32_16x16x32_bf16(f[kk * 2], b, acc[0][n], 0, 0, 0);
      acc[1][n] = __builtin_amdgcn_mfma_f32_16x16x32_bf16(f[kk * 2 + 1], b, acc[1][n], 0, 0, 0);
    }
  }
}

// C layout: col = lane&15, row = (lane>>4)*4 + reg
__device__ __forceinline__ void store_half(const f32x4 acc[2][4], u16* outb, int rw, int nh,
                                           int g, int j, bool relu) {
  #pragma unroll
  for (int m = 0; m < 2; ++m)
    #pragma unroll
    for (int n = 0; n < 4; ++n)
      #pragma unroll
      for (int r = 0; r < 4; ++r) {
        float v = acc[m][n][r];
        if (relu) v = fmaxf(v, 0.f);
        int row = rw + m * 16 + g * 4 + r;
        int c = nh * 64 + n * 16 + j;
        int byte = (row * 256 + c * 2) ^ ((row & 7) << 4);
        *(u16*)((char*)outb + byte) = f2bf(v);
      }
}

// in-place K=128 -> N=128 layer: frags to regs first, then overwrite same rows
__device__ __forceinline__ void layer_ip(u16* buf, const u16* __restrict__ Wt,
                                         const float* __restrict__ bias, int rw, int g, int j) {
  bf16x8 f[8];
  load_frags(buf, rw, g, j, f);
  #pragma unroll
  for (int nh = 0; nh < 2; ++nh) {
    f32x4 acc[2][4];
    init_half(acc, bias, nh, j);
    gemm_half_f(f, Wt, nh, acc, g, j);
    store_half(acc, buf, rw, nh, g, j, true);
  }
}

// gather this wave's 32 node rows (fp32) -> bf16 swizzled LDS tile; 2 lanes/row
__device__ __forceinline__ void stage(const float* __restrict__ x, const int* __restrict__ idx,
                                      int e0, u16* buf, int rw, int lane) {
  int rl = rw + (lane >> 1);   // wave-private rows rw..rw+31
  int sub = lane & 1;          // 64-float half of the feature row
  int e = e0 + rl;
  if (e >= NE) e = NE - 1;
  int node = idx[e];
  const f32x4* src = (const f32x4*)(x + (size_t)node * 128 + sub * 64);
  #pragma unroll
  for (int c = 0; c < 8; ++c) {
    f32x4 v0 = src[c * 2];
    f32x4 v1 = src[c * 2 + 1];
    bf16x8 o;
    o[0] = (short)f2bf(v0[0]); o[1] = (short)f2bf(v0[1]);
    o[2] = (short)f2bf(v0[2]); o[3] = (short)f2bf(v0[3]);
    o[4] = (short)f2bf(v1[0]); o[5] = (short)f2bf(v1[1]);
    o[6] = (short)f2bf(v1[2]); o[7] = (short)f2bf(v1[3]);
    int col = sub * 64 + c * 8;
    int byte = (rl * 256 + col * 2) ^ ((rl & 7) << 4);
    *(bf16x8*)((char*)buf + byte) = o;
  }
}

// ---------------- main fused kernel: 1 block = 128 edges, 4 waves x 32 wave-private rows ----
// SINGLE activation buffer (in-place layers via register-held A-fragments) =>
// LDS ~35 KB => 4 blocks/CU at 128 VGPRs (16 waves/CU). No inter-phase barriers
// (all LDS rows wave-private; same-wave DS ops are in-order — validated r7/r8).
// launch_bounds(256,2) caps VGPR at 128; n-split keeps peak live ~90 => no spill.
__global__ __launch_bounds__(256, 2) void vae_kernel(
    const float* __restrict__ x, const int* __restrict__ rowi, const int* __restrict__ coli,
    const float* __restrict__ eps, const u16* __restrict__ wsu, double* __restrict__ accg,
    float* __restrict__ out) {
  __shared__ __align__(16) u16 buf[128 * 128];   // 32 KB
  __shared__ __align__(16) u16 zbuf[128 * 8];    // 2 KB, [row][8], cols 5..7 zero
  __shared__ float redr[4], redk[4];

  const float* wsf = (const float*)wsu;
  const int tid = threadIdx.x;
  const int lane = tid & 63;
  const int wave = tid >> 6;
  const int g = lane >> 4;
  const int j = lane & 15;
  const int rw = wave * 32;
  const int e0 = blockIdx.x * 128;

  // zero this wave's zbuf rows
  if (lane < 32) {
    bf16x8 zz = {};
    *(bf16x8*)(zbuf + (rw + lane) * 8) = zz;
  }

  float kl_part = 0.f, rl_part = 0.f;

  // ---- stage row-half, capture frags, stage col-half over it, capture frags ----
  stage(x, rowi, e0, buf, rw, lane);
  bf16x8 fA[8];
  load_frags(buf, rw, g, j, fA);
  stage(x, coli, e0, buf, rw, lane);   // same-wave DS in-order: reads above already serviced
  bf16x8 fB[8];
  load_frags(buf, rw, g, j, fB);

  // ---- enc0: K=256 from fA,fB; n-split; store -> buf ----
  #pragma unroll
  for (int nh = 0; nh < 2; ++nh) {
    f32x4 acc[2][4];
    init_half(acc, wsf + BIAS_F + BE0_F, nh, j);
    #pragma unroll
    for (int kk = 0; kk < 4; ++kk) {
      int k = kk * 32 + g * 8;
      #pragma unroll
      for (int n = 0; n < 4; ++n) {
        bf16x8 b0 = *(const bf16x8*)(wsu + WE0_U + ((nh * 4 + n) * 16 + j) * 256 + k);
        bf16x8 b1 = *(const bf16x8*)(wsu + WE0_U + ((nh * 4 + n) * 16 + j) * 256 + 128 + k);
        acc[0][n] = __builtin_amdgcn_mfma_f32_16x16x32_bf16(fA[kk * 2], b0, acc[0][n], 0, 0, 0);
        acc[1][n] = __builtin_amdgcn_mfma_f32_16x16x32_bf16(fA[kk * 2 + 1], b0, acc[1][n], 0, 0, 0);
        acc[0][n] = __builtin_amdgcn_mfma_f32_16x16x32_bf16(fB[kk * 2], b1, acc[0][n], 0, 0, 0);
        acc[1][n] = __builtin_amdgcn_mfma_f32_16x16x32_bf16(fB[kk * 2 + 1], b1, acc[1][n], 0, 0, 0);
      }
    }
    store_half(acc, buf, rw, nh, g, j, true);
  }

  // ---- enc1, enc2 (in-place) ----
  layer_ip(buf, wsu + WE1_U, wsf + BIAS_F + BE1_F, rw, g, j);
  layer_ip(buf, wsu + WE2_U, wsf + BIAS_F + BE2_F, rw, g, j);

  // ---- enc3: N=16 (cols 0..4 mu, 5..9 logvar) ----
  f32x4 a3[2];
  {
    bf16x8 f3[8];
    load_frags(buf, rw, g, j, f3);
    f32x4 v = bcast4(wsf[BIAS_F + BE3_F + j]);
    a3[0] = v;
    a3[1] = v;
    #pragma unroll
    for (int kk = 0; kk < 4; ++kk) {
      int k = kk * 32 + g * 8;
      bf16x8 b = *(const bf16x8*)(wsu + WE3_U + j * 128 + k);
      a3[0] = __builtin_amdgcn_mfma_f32_16x16x32_bf16(f3[kk * 2], b, a3[0], 0, 0, 0);
      a3[1] = __builtin_amdgcn_mfma_f32_16x16x32_bf16(f3[kk * 2 + 1], b, a3[1], 0, 0, 0);
    }
  }

  // ---- reparameterization + KL (within-wave) ----
  {
    int src = g * 16 + ((j + 5) & 15);
    #pragma unroll
    for (int m = 0; m < 2; ++m)
      #pragma unroll
      for (int r = 0; r < 4; ++r) {
        float muv = a3[m][r];
        float lvv = __shfl(a3[m][r], src, 64);
        if (j < 5) {
          int row = rw + m * 16 + g * 4 + r;
          int e = e0 + row;
          int ec = e < NE ? e : NE - 1;
          float stdv = __expf(0.5f * lvv);
          float zv = muv + eps[(size_t)ec * 5 + j] * stdv;
          zbuf[row * 8 + j] = f2bf(zv);
          if (e < NE) kl_part += 1.0f + lvv - muv * muv - __expf(lvv);
        }
      }
  }

  // ---- dec0: z (K=32, only g==0 has nonzero k) -> buf ----
  {
    bf16x8 zf0 = {}, zf1 = {};
    if (g == 0) {
      zf0 = *(const bf16x8*)(zbuf + (rw + j) * 8);
      zf1 = *(const bf16x8*)(zbuf + (rw + 16 + j) * 8);
    }
    #pragma unroll
    for (int nh = 0; nh < 2; ++nh) {
      f32x4 acc[2][4];
      init_half(acc, wsf + BIAS_F + BD0_F, nh, j);
      int k = g * 8;
      #pragma unroll
      for (int n = 0; n < 4; ++n) {
        bf16x8 b = *(const bf16x8*)(wsu + WD0_U + ((nh * 4 + n) * 16 + j) * 32 + k);
        acc[0][n] = __builtin_amdgcn_mfma_f32_16x16x32_bf16(zf0, b, acc[0][n], 0, 0, 0);
        acc[1][n] = __builtin_amdgcn_mfma_f32_16x16x32_bf16(zf1, b, acc[1][n], 0, 0, 0);
      }
      store_half(acc, buf, rw, nh, g, j, true);
    }
  }

  // ---- dec1, dec2 (in-place) ----
  layer_ip(buf, wsu + WD1_U, wsf + BIAS_F + BD1_F, rw, g, j);
  layer_ip(buf, wsu + WD2_U, wsf + BIAS_F + BD2_F, rw, g, j);

  // ---- loss node indices (hide latency under dec3) ----
  int rn[2][4], cn[2][4];
  #pragma unroll
  for (int m = 0; m < 2; ++m)
    #pragma unroll
    for (int r = 0; r < 4; ++r) {
      int e = e0 + rw + m * 16 + g * 4 + r;
      int ec = e < NE ? e : NE - 1;
      rn[m][r] = rowi[ec];
      cn[m][r] = coli[ec];
    }

  // ---- dec3 (N=256 in 4 quarters) fused with recon loss ----
  float rlsq[2][4] = {{0.f, 0.f, 0.f, 0.f}, {0.f, 0.f, 0.f, 0.f}};
  {
    bf16x8 f[8];
    load_frags(buf, rw, g, j, f);
    #pragma unroll
    for (int qh = 0; qh < 4; ++qh) {
      f32x4 acc[2][4];
      init_half(acc, wsf + BIAS_F + BD3_F, qh, j);
      gemm_half_f(f, wsu + WD3_U, qh, acc, g, j);
      #pragma unroll
      for (int m = 0; m < 2; ++m)
        #pragma unroll
        for (int n = 0; n < 4; ++n)
          #pragma unroll
          for (int r = 0; r < 4; ++r) {
            int c = qh * 64 + n * 16 + j;
            int node = (c < 128) ? rn[m][r] : cn[m][r];
            float pv = x[(size_t)node * 128 + (c & 127)];
            float d = acc[m][n][r] - pv;
            rlsq[m][r] += d * d;
          }
    }
  }

  // per-row reduce over 16 col-lanes -> rl, affinity
  #pragma unroll
  for (int m = 0; m < 2; ++m)
    #pragma unroll
    for (int r = 0; r < 4; ++r) {
      float v = rlsq[m][r];
      v += __shfl_xor(v, 1);
      v += __shfl_xor(v, 2);
      v += __shfl_xor(v, 4);
      v += __shfl_xor(v, 8);
      if (j == 0) {
        int e = e0 + rw + m * 16 + g * 4 + r;
        if (e < NE) {
          float rl = sqrtf(v);
          out[e] = 1.0f / (1.0f + 3.5f * rl);
          rl_part += rl;
        }
      }
    }

  // ---- block reduction (the ONLY barrier) + global double atomics ----
  float kv = kl_part, rv = rl_part;
  #pragma unroll
  for (int msk = 1; msk < 64; msk <<= 1) {
    kv += __shfl_xor(kv, msk);
    rv += __shfl_xor(rv, msk);
  }
  if (lane == 0) {
    redk[wave] = kv;
    redr[wave] = rv;
  }
  __syncthreads();
  if (tid == 0) {
    atomicAdd(&accg[0], (double)(redr[0] + redr[1] + redr[2] + redr[3]));
    atomicAdd(&accg[1], (double)(redk[0] + redk[1] + redk[2] + redk[3]));
  }
}

// ---------------- finalize ----------------
__global__ void fin_kernel(const double* __restrict__ accg, float* __restrict__ out) {
  if (threadIdx.x == 0) {
    out[NE] = (float)(accg[0] / (double)NE);
    out[NE + 1] = (float)(accg[1] * (-0.5 * 10.0 / ((double)NE * 5.0)));
  }
}

extern "C" void kernel_launch(void* const* d_in, const int* in_sizes, int n_in,
                              void* d_out, int out_size, void* d_ws, size_t ws_size,
                              hipStream_t stream) {
  (void)in_sizes; (void)n_in; (void)out_size; (void)ws_size;
  const float* x   = (const float*)d_in[0];
  const int*   row = (const int*)d_in[1];
  const int*   col = (const int*)d_in[2];
  const float* eps = (const float*)d_in[3];
  u16* wsu = (u16*)d_ws;
  double* accg = (double*)((char*)d_ws + ACC_BYTE);
  float* out = (float*)d_out;

  prep_kernel<<<541, 256, 0, stream>>>(
      (const float*)d_in[4],  (const float*)d_in[5],  (const float*)d_in[6],  (const float*)d_in[7],
      (const float*)d_in[8],  (const float*)d_in[9],  (const float*)d_in[10], (const float*)d_in[11],
      (const float*)d_in[12], (const float*)d_in[13], (const float*)d_in[14], (const float*)d_in[15],
      (const float*)d_in[16], (const float*)d_in[17], (const float*)d_in[18], (const float*)d_in[19],
      wsu);
  vae_kernel<<<NBLOCKS, 256, 0, stream>>>(x, row, col, eps, wsu, accg, out);
  fin_kernel<<<1, 64, 0, stream>>>(accg, out);
}